// Round 2
// baseline (78.900 us; speedup 1.0000x reference)
//
#include <hip/hip_runtime.h>
#include <math.h>

#define N 1024
#define D 256
#define D4 (D / 4)        /* 64 float4 per row */
#define EPSF 1e-8f
#define B 16              /* blocks in fused kernel */
#define RPB (N / B)       /* 64 rows per block in phase B */

// Fused KoLeo kernel.
//
// Phase A: every block (redundantly) computes y[r] = X[r][0] / max(||X_r||, eps)
//   for all 1024 rows into LDS. 8 lanes per row, 32 rows per pass, 32 passes.
//   X is 1 MB -> L2-resident after the first iteration; redundancy costs ~1 us.
//   (Redundant recompute avoids a second kernel node + inter-node dependency,
//    which dominated the non-fill time: real compute here is only ~2-4 us.)
//
// Phase B: m_i = min_{j != i} |y_j - y_i| for this block's 64 rows, scanning
//   LDS with ds_read_b128 (4 candidates per LDS issue; the old kernel was
//   LDS-issue-bound on scalar ds_read_b32).
//
// Epilogue: one atomicAdd(out, part) per block (out pre-zeroed by a 4-byte
//   memset node); block 0 adds the -(d-1)*log(eps) constant. No ticket chain.
__global__ void __launch_bounds__(256) koleo_fused(const float* __restrict__ X,
                                                   float* __restrict__ out) {
    __shared__ float sy[N];
    const int tid = threadIdx.x;

    // ---------------- Phase A ----------------
    {
        const int g = tid >> 3;   // row-group within pass: 0..31
        const int s = tid & 7;    // lane within row: 0..7
        const float4* X4 = (const float4*)X;
        for (int pass = 0; pass < 32; ++pass) {
            const int r = pass * 32 + g;
            const float4* row = X4 + r * D4;
            float ss = 0.0f;
            float x0 = 0.0f;
            #pragma unroll
            for (int it = 0; it < 8; ++it) {
                const float4 v = row[s + (it << 3)];
                if (it == 0) x0 = v.x;          // lane s==0, it==0 holds X[r][0]
                ss += v.x * v.x + v.y * v.y + v.z * v.z + v.w * v.w;
            }
            // sum across the 8-lane row group (xor masks < 8 stay in-group)
            #pragma unroll
            for (int off = 4; off > 0; off >>= 1)
                ss += __shfl_xor(ss, off, 64);
            if (s == 0)
                sy[r] = x0 / fmaxf(sqrtf(ss), EPSF);
        }
    }
    __syncthreads();

    // ---------------- Phase B ----------------
    const int grp = tid >> 2;              // 0..63: row within this block
    const int s   = tid & 3;               // 0..3 : sublane within row group
    const int i   = blockIdx.x * RPB + grp;
    const float yi = sy[i];
    const float4* sy4 = (const float4*)sy;

    float m = INFINITY;
    #pragma unroll 8
    for (int t = 0; t < 64; ++t) {
        const int q  = s + (t << 2);       // float4 index 0..255
        const float4 v = sy4[q];           // broadcast across the 16 row-groups
        const int jb = q << 2;
        float d0 = fabsf(v.x - yi);
        float d1 = fabsf(v.y - yi);
        float d2 = fabsf(v.z - yi);
        float d3 = fabsf(v.w - yi);
        d0 = (jb + 0 == i) ? INFINITY : d0;
        d1 = (jb + 1 == i) ? INFINITY : d1;
        d2 = (jb + 2 == i) ? INFINITY : d2;
        d3 = (jb + 3 == i) ? INFINITY : d3;
        m = fminf(m, fminf(fminf(d0, d1), fminf(d2, d3)));
    }
    // min across the 4-lane row group
    #pragma unroll
    for (int off = 2; off > 0; off >>= 1)
        m = fminf(m, __shfl_xor(m, off, 64));

    // -log(m+eps)/N on each row-group leader, then full-wave sum
    float val = (s == 0) ? (-logf(m + EPSF) * (1.0f / (float)N)) : 0.0f;
    #pragma unroll
    for (int off = 32; off > 0; off >>= 1)
        val += __shfl_down(val, off, 64);

    __shared__ float wsum[4];
    if ((tid & 63) == 0) wsum[tid >> 6] = val;
    __syncthreads();

    if (tid == 0) {
        float part = wsum[0] + wsum[1] + wsum[2] + wsum[3];
        // k>=1 features contribute exactly -(d-1)*log(eps) after /n
        if (blockIdx.x == 0) part += -255.0f * logf(EPSF);
        atomicAdd(out, part);
    }
}

extern "C" void kernel_launch(void* const* d_in, const int* in_sizes, int n_in,
                              void* d_out, int out_size, void* d_ws, size_t ws_size,
                              hipStream_t stream) {
    // Zero the scalar output; blocks accumulate into it directly.
    hipMemsetAsync(d_out, 0, out_size, stream);
    koleo_fused<<<B, 256, 0, stream>>>((const float*)d_in[0], (float*)d_out);
}

// Round 3
// 56.236 us; speedup vs baseline: 1.4030x; 1.4030x over previous
//
#include <hip/hip_runtime.h>
#include <math.h>

#define N 1024
#define D 256
#define EPSF 1e-8f
#define K2_BLOCKS 128

// Kernel 1: per-row L2 norm of X[1024][256]; y[i] = X[i][0]/max(||X_i||,eps).
// One 64-lane wave per row (1024 waves total): max parallel-miss coverage for
// the COLD X read (the harness's 268MB poison fill flushes L2+L3 every iter).
// Block 0 also overwrites the poisoned out[0] with the bias term, so k2 can
// accumulate straight into out with no accum/ticket/fence machinery.
__global__ void __launch_bounds__(256) rownorm_kernel(const float* __restrict__ X,
                                                      float* __restrict__ y,
                                                      float* __restrict__ out) {
    const int tid  = threadIdx.x;
    const int wave = tid >> 6;
    const int lane = tid & 63;
    const int row  = blockIdx.x * 4 + wave;

    const float4 v = ((const float4*)(X + row * D))[lane];
    float ss = v.x * v.x + v.y * v.y + v.z * v.z + v.w * v.w;
    #pragma unroll
    for (int off = 32; off > 0; off >>= 1)
        ss += __shfl_down(ss, off, 64);

    if (lane == 0) {
        // lane 0's v.x is X[row*D + 0]
        y[row] = v.x / fmaxf(sqrtf(ss), EPSF);
    }
    // Features 1..255 contribute exactly -(D-1)*log(eps) after /n.
    // Plain store beats the poison; visible to k2 via kernel boundary.
    if (blockIdx.x == 0 && tid == 0)
        out[0] = -255.0f * logf(EPSF);
}

// Kernel 2: m_i = min_{j != i} |y_j - y_i|; each block atomicAdds its partial
// sum of -log(m_i+eps)/N directly into out (pre-seeded by k1). No ticket, no
// fence, no finalize read-back.
// 128 blocks x 256 threads; 32 lanes per row i (8 rows/block); float4 LDS scan.
__global__ void __launch_bounds__(256) koleo_kernel(const float* __restrict__ y,
                                                    float* __restrict__ out) {
    __shared__ float sy[N];
    const int tid = threadIdx.x;
    ((float4*)sy)[tid] = ((const float4*)y)[tid];   // 256 * 16B = full 4KB
    __syncthreads();

    const int grp = tid >> 5;        // 0..7 : which row within this block
    const int s   = tid & 31;        // 0..31: sublane within the row group
    const int i   = blockIdx.x * 8 + grp;
    const float yi = sy[i];
    const float4* sy4 = (const float4*)sy;

    float m = INFINITY;
    #pragma unroll
    for (int t = 0; t < 8; ++t) {
        const int q  = s + (t << 5);      // float4 index 0..255
        const float4 v = sy4[q];
        const int jb = q << 2;
        float d0 = fabsf(v.x - yi);
        float d1 = fabsf(v.y - yi);
        float d2 = fabsf(v.z - yi);
        float d3 = fabsf(v.w - yi);
        d0 = (jb + 0 == i) ? INFINITY : d0;
        d1 = (jb + 1 == i) ? INFINITY : d1;
        d2 = (jb + 2 == i) ? INFINITY : d2;
        d3 = (jb + 3 == i) ? INFINITY : d3;
        m = fminf(m, fminf(fminf(d0, d1), fminf(d2, d3)));
    }
    // min across the 32-lane subgroup (xor masks < 32 stay within subgroup)
    #pragma unroll
    for (int off = 16; off > 0; off >>= 1)
        m = fminf(m, __shfl_xor(m, off, 64));

    float val = (s == 0) ? (-logf(m + EPSF) * (1.0f / (float)N)) : 0.0f;
    // sum across the full 64-lane wave (picks up both subgroups' s==0 lanes)
    #pragma unroll
    for (int off = 32; off > 0; off >>= 1)
        val += __shfl_down(val, off, 64);

    __shared__ float wsum[4];
    if ((tid & 63) == 0) wsum[tid >> 6] = val;
    __syncthreads();

    if (tid == 0) {
        const float part = wsum[0] + wsum[1] + wsum[2] + wsum[3];
        atomicAdd(out, part);
    }
}

extern "C" void kernel_launch(void* const* d_in, const int* in_sizes, int n_in,
                              void* d_out, int out_size, void* d_ws, size_t ws_size,
                              hipStream_t stream) {
    const float* X = (const float*)d_in[0];
    float* out = (float*)d_out;
    float* y   = (float*)d_ws;   // [0..1023]

    rownorm_kernel<<<N / 4, 256, 0, stream>>>(X, y, out);
    koleo_kernel<<<K2_BLOCKS, 256, 0, stream>>>(y, out);
}